// Round 8
// baseline (448.606 us; speedup 1.0000x reference)
//
#include <hip/hip_runtime.h>
#include <hip/hip_bf16.h>

typedef _Float16 half8 __attribute__((ext_vector_type(8)));
typedef _Float16 half4 __attribute__((ext_vector_type(4)));
typedef _Float16 half2v __attribute__((ext_vector_type(2)));
typedef float float4v __attribute__((ext_vector_type(4)));

#define BATCH 32768
#define TT 30

#if __has_builtin(__builtin_amdgcn_exp2f)
#define FEXP2(x) __builtin_amdgcn_exp2f(x)
#else
#define FEXP2(x) __expf((x) * 0.6931471805599453f)
#endif
#if __has_builtin(__builtin_amdgcn_rcpf)
#define FRCP(x) __builtin_amdgcn_rcpf(x)
#else
#define FRCP(x) (1.0f / (x))
#endif

#define NLOG2E  -1.4426950408889634f
#define N2LOG2E -2.8853900817779268f

// ws offsets (floats). Gate weights PRESCALED (-log2e; gate g -2log2e).
// SWAPPED-OPERAND GEMMs: W frags are the A operand (row=lane&15=unit),
// z frags the B operand (col=lane&15=agent).  D: lane holds 4 UNITS x
// 1 AGENT -> h/x/pred writes are contiguous half4 (b64).
// Gate bias is folded into the K-pad column: z[k=80]=1.0, W[k=80]=bias.
#define WFRAG_OFF 0        // f16[4 wv][4 gate][3 ks][64 lane][8] = 24576 halves
#define WCF_OFF   12288    // f16[2 role][2 ks][64 lane][8] = 2048 halves
#define BIASB_OFF 13312    // f32[256]  (unused by lstm; kept)
#define SXY_OFF   13568    // f32[16][3]   (Sx, Sy, bse)
#define CBIAS_OFF 13616    // f32[2][16]   (role0: bpos|0, role1: bx)
#define WCONF_OFF 13648    // f32[384]
#define BCONF_OFF 14032    // f32[6]
#define FLAG_IDX  14038    // int: 1 => inputs fp32, 0 => bf16
#define CONF_BASE (BATCH * 360)

__global__ void detect_kernel(const unsigned short* __restrict__ raw,
                              int* __restrict__ flag_out) {
    __shared__ int sflag[256];
    int local = 0;
    for (int i = threadIdx.x; i < 16384; i += 256) {
        unsigned short u = raw[i];
        if ((u & 0x7F80u) == 0x7F80u) local = 1;
    }
    sflag[threadIdx.x] = local;
    __syncthreads();
    if (threadIdx.x == 0) {
        int f = 0;
        for (int i = 0; i < 256; ++i) f |= sflag[i];
        flag_out[0] = f;
    }
}

__device__ __forceinline__ float ldin(const void* p, int i, int isf32) {
    return isf32 ? ((const float*)p)[i]
                 : (float)((const __hip_bfloat16*)p)[i];
}

__global__ void prep_kernel(const void* __restrict__ W_ih,
                            const void* __restrict__ W_hh,
                            const void* __restrict__ b_ih,
                            const void* __restrict__ b_hh,
                            const void* __restrict__ W_se,
                            const void* __restrict__ b_se,
                            const void* __restrict__ W_pos,
                            const void* __restrict__ b_pos,
                            const void* __restrict__ W_conf,
                            const void* __restrict__ b_conf,
                            float* __restrict__ ws)
{
    const int isf32 = ((const int*)(ws + FLAG_IDX))[0];
    int tid = blockIdx.x * blockDim.x + threadIdx.x;
    int stride = gridDim.x * blockDim.x;
    _Float16* wfh = (_Float16*)ws;

    // Gate-GEMM W fragments, 16x16x32 tiles, K padded to 96.
    // k==80 carries the (prescaled) gate bias; z[k=80]=1 in the kernel.
    for (int idx = tid; idx < 24576; idx += stride) {
        int jj = idx & 7, r = idx >> 3;
        int lane = r & 63; r >>= 6;
        int ks = r % 3; r /= 3;
        int gate = r & 3; int wv = r >> 2;
        int col = lane & 15, akq = lane >> 4;
        int k = ks * 32 + akq * 8 + jj;
        int row = gate * 64 + wv * 16 + col;
        float v = 0.f;
        if (k < 16) v = ldin(W_ih, row * 16 + k, isf32);
        else if (k < 80) v = ldin(W_hh, row * 64 + (k - 16), isf32);
        else if (k == 80) v = ldin(b_ih, row, isf32) + ldin(b_hh, row, isf32);
        v *= (gate == 2) ? N2LOG2E : NLOG2E;
        wfh[idx] = (_Float16)v;
    }
    // Fused C-GEMM fragments: role0 = Wpos (rel), role1 = M=Wse*Wpos (x).
    _Float16* wch = (_Float16*)(ws + WCF_OFF);
    for (int idx = tid; idx < 2048; idx += stride) {
        int jj = idx & 7, r = idx >> 3;
        int lane = r & 63; r >>= 6;
        int ks = r & 1, role = r >> 1;
        int col = lane & 15, akq = lane >> 4;
        int k = ks * 32 + akq * 8 + jj;   // 0..63 over h
        float v = 0.f;
        if (role == 0) {
            if (col < 12) v = ldin(W_pos, col * 64 + k, isf32);
        } else {
            float s = 0.f;
            for (int p = 0; p < 12; ++p)
                s += ldin(W_se, col * 12 + p, isf32) * ldin(W_pos, p * 64 + k, isf32);
            v = s;
        }
        wch[idx] = (_Float16)v;
    }
    for (int idx = tid; idx < 256; idx += stride) {
        int gate = idx >> 6;
        float scale = (gate == 2) ? N2LOG2E : NLOG2E;
        ws[BIASB_OFF + idx] = (ldin(b_ih, idx, isf32) + ldin(b_hh, idx, isf32)) * scale;
    }
    for (int idx = tid; idx < 16; idx += stride) {
        float sx = 0.f, sy = 0.f;
        for (int m = 0; m < 6; ++m) {
            sx += ldin(W_se, idx * 12 + 2 * m, isf32);
            sy += ldin(W_se, idx * 12 + 2 * m + 1, isf32);
        }
        ws[SXY_OFF + idx * 3 + 0] = sx;
        ws[SXY_OFF + idx * 3 + 1] = sy;
        ws[SXY_OFF + idx * 3 + 2] = ldin(b_se, idx, isf32);
    }
    for (int idx = tid; idx < 32; idx += stride) {
        int w = idx >> 4, cc = idx & 15;
        float v = 0.f;
        if (w == 0) {
            if (cc < 12) v = ldin(b_pos, cc, isf32);
        } else {
            float s = ldin(b_se, cc, isf32);
            for (int p = 0; p < 12; ++p)
                s += ldin(W_se, cc * 12 + p, isf32) * ldin(b_pos, p, isf32);
            v = s;
        }
        ws[CBIAS_OFF + idx] = v;
    }
    for (int idx = tid; idx < 384; idx += stride)
        ws[WCONF_OFF + idx] = ldin(W_conf, idx, isf32);
    for (int idx = tid; idx < 6; idx += stride)
        ws[BCONF_OFF + idx] = ldin(b_conf, idx, isf32);
}

// OCCUPANCY KERNEL: block = 256 thr (4 waves), 16 agents (ONE group),
// grid 2048 -> 8 blocks/CU = 32 waves/CU = 8 waves/SIMD, each wave on a
// SIMD from a DIFFERENT block (no shared barriers) -> dependency stalls in
// one wave covered by 7 independent streams.  LDS 9.6 KB: zsh [16][168] +
// predh 11-slot ring [16 agents][11][12] flushed in 10-step chunks at
// t=10/20/end (slots mod 11 disjoint from concurrent writes -> flush rides
// inside the S1 slot, zero extra barriers).  Schedule (2 barriers/step):
//   S1: AB(t) all waves (+ ring flush at t=10,20)   -- bar
//   S2: wave0 rel->ring, wave1 x->z                 -- bar
// z row (stride 168 halves): [x 0..15 | pad 16..31 (16->1.0 bias) |
// h_par0 32..95 | h_par1 96..159].
__global__ __launch_bounds__(256, 8) void lstm_kernel(
    const void* __restrict__ traj_rel,
    const void* __restrict__ h0,
    const void* __restrict__ c0,
    const float* __restrict__ ws,
    float* __restrict__ out)
{
    __shared__ __align__(16) _Float16 zsh[16 * 168];
    __shared__ __align__(16) _Float16 predh[16 * 11 * 12];  // [agent][slot][p]

    const int tid = threadIdx.x;
    const int lane = tid & 63;
    const int wid = __builtin_amdgcn_readfirstlane(tid >> 6);  // wave id 0..3
    const int col16 = lane & 15;        // agent (D col)
    const int akq = lane >> 4;          // 0..3 (D row quarter)
    const int base = blockIdx.x * 16;
    const int isf32 = ((const int*)(ws + FLAG_IDX))[0];

    // ---- per-lane constants ----
    const float4v* wfg = (const float4v*)ws;
    half8 Bf[4][3];
#pragma unroll
    for (int tl = 0; tl < 4; ++tl)
#pragma unroll
        for (int ks = 0; ks < 3; ++ks)
            Bf[tl][ks] = __builtin_bit_cast(half8,
                wfg[((wid * 4 + tl) * 3 + ks) * 64 + lane]);
    // C-phase fragments: wave0 = rel, wave1 = x (others unused)
    const int role = wid & 1;
    half8 wfc[2];
    {
        const float4v* wcg = (const float4v*)(ws + WCF_OFF);
#pragma unroll
        for (int ks = 0; ks < 2; ++ks)
            wfc[ks] = __builtin_bit_cast(half8, wcg[(role * 2 + ks) * 64 + lane]);
    }
    const float4v cb4 = *(const float4v*)&ws[CBIAS_OFF + role * 16 + akq * 4];

    // ---- c state: cell (agent col16, unit wid*16 + akq*4 + i) ----
    float c[4];
#pragma unroll
    for (int i = 0; i < 4; ++i)
        c[i] = ldin(c0, (base + col16) * 64 + wid * 16 + akq * 4 + i, isf32);

    // ---- init z: h0 -> par0, x0, k-pad (1.0 at k=80) ----
    {
        int m = tid & 15, jq2 = tid >> 4;   // agent, chunk 0..15
        _Float16* zr = &zsh[m * 168];
        if (jq2 < 8) {                       // h0 chunk
            half8 ha;
#pragma unroll
            for (int i = 0; i < 8; ++i)
                ha[i] = (_Float16)ldin(h0, (base + m) * 64 + jq2 * 8 + i, isf32);
            *(half8*)&zr[32 + jq2 * 8] = ha;
        } else if (jq2 < 12) {               // x0 half4
            int jx = jq2 - 8;
            float rx = ldin(traj_rel, 2 * (base + m), isf32);
            float ry = ldin(traj_rel, 2 * (base + m) + 1, isf32);
            half4 xs;
#pragma unroll
            for (int i = 0; i < 4; ++i) {
                int e = 4 * jx + i;
                float x = fmaf(rx, ws[SXY_OFF + e * 3],
                          fmaf(ry, ws[SXY_OFF + e * 3 + 1], ws[SXY_OFF + e * 3 + 2]));
                xs[i] = (_Float16)(x > 0.f ? x : 0.01f * x);
            }
            *(half4*)&zr[4 * jx] = xs;
        } else if (jq2 == 12) {              // k = 80..87: bias col (k80 = 1)
            half8 zz = {};
            zz[0] = (_Float16)1.0f;
            *(half8*)&zr[16] = zz;
        } else if (jq2 == 13) {              // k = 88..95: zeros
            half8 zz = {};
            *(half8*)&zr[24] = zz;
        }
    }
    __syncthreads();

    // ---- precomputed LDS addresses (halves) ----
    int aoff[2][3];   // z B-frag base per parity per ks (chunk-mapped)
#pragma unroll
    for (int p = 0; p < 2; ++p)
#pragma unroll
        for (int ks = 0; ks < 3; ++ks) {
            int q = ks * 4 + akq;          // global k-chunk 0..11
            int off = (q < 2) ? q * 8
                    : (q < 10) ? 32 + p * 64 + (q - 2) * 8
                               : 16 + (q - 10) * 8;
            aoff[p][ks] = col16 * 168 + off;
        }
    const int zcb = col16 * 168 + 32 + akq * 8;      // C h-read (+P*64 +ks*32)
    const int hw4 = col16 * 168 + 32 + wid * 16 + akq * 4;  // h-write (+PN*64)
    const int xw4 = col16 * 168 + akq * 4;           // x-write

#define SLOT(T) ((T) - ((T) >= 22 ? 22 : (T) >= 11 ? 11 : 0))

#define PHASE_AB(PC, PN) do {                                                 \
    float4v acc_[4];                                                          \
    _Pragma("unroll")                                                         \
    for (int g = 0; g < 4; ++g) {                                             \
        acc_[g][0] = 0.f; acc_[g][1] = 0.f; acc_[g][2] = 0.f; acc_[g][3] = 0.f;\
    }                                                                         \
    _Pragma("unroll")                                                         \
    for (int ks = 0; ks < 3; ++ks) {                                          \
        half8 af_ = *(const half8*)&zsh[aoff[PC][ks]];                        \
        _Pragma("unroll")                                                     \
        for (int g = 0; g < 4; ++g)                                           \
            acc_[g] = __builtin_amdgcn_mfma_f32_16x16x32_f16(                 \
                Bf[g][ks], af_, acc_[g], 0, 0, 0);                            \
    }                                                                         \
    half4 hv_;                                                                \
    _Pragma("unroll")                                                         \
    for (int i = 0; i < 4; ++i) {                                             \
        float ei = FEXP2(acc_[0][i]);                                         \
        float ef = FEXP2(acc_[1][i]);                                         \
        float eg = FEXP2(acc_[2][i]);                                         \
        float eo = FEXP2(acc_[3][i]);                                         \
        float pp = (1.f + ei) * (1.f + eg);                                   \
        float qq = 1.f + ef;                                                  \
        float cn = fmaf(c[i], pp, (1.f - eg) * qq) * FRCP(pp * qq);           \
        c[i] = cn;                                                            \
        float ec = FEXP2(cn * N2LOG2E);                                       \
        float hn = (1.f - ec) * FRCP((1.f + eo) * (1.f + ec));                \
        hv_[i] = (_Float16)hn;                                                \
    }                                                                         \
    *(half4*)&zsh[hw4 + (PN) * 64] = hv_;                                     \
} while (0)

#define PHASE_C(P, T, LAST) do {                                              \
    if (wid < 2) {                                                            \
        float4v racc_;                                                        \
        racc_[0] = cb4[0]; racc_[1] = cb4[1];                                 \
        racc_[2] = cb4[2]; racc_[3] = cb4[3];                                 \
        _Pragma("unroll")                                                     \
        for (int ks = 0; ks < 2; ++ks) {                                      \
            half8 af_ = *(const half8*)&zsh[zcb + (P) * 64 + ks * 32];        \
            racc_ = __builtin_amdgcn_mfma_f32_16x16x32_f16(                   \
                wfc[ks], af_, racc_, 0, 0, 0);                                \
        }                                                                     \
        if (wid == 0) {                                                       \
            if (akq < 3) {                                                    \
                int st_ = SLOT(T);                                            \
                half4 pv_;                                                    \
                _Pragma("unroll")                                             \
                for (int i = 0; i < 4; ++i) pv_[i] = (_Float16)racc_[i];      \
                *(half4*)&predh[(col16 * 11 + st_) * 12 + akq * 4] = pv_;     \
            }                                                                 \
        } else if (!(LAST)) {                                                 \
            half4 xv4_;                                                       \
            _Pragma("unroll")                                                 \
            for (int i = 0; i < 4; ++i) {                                     \
                float xv_ = racc_[i];                                         \
                xv4_[i] = (_Float16)(xv_ > 0.f ? xv_ : 0.01f * xv_);          \
            }                                                                 \
            *(half4*)&zsh[xw4] = xv4_;                                        \
        }                                                                     \
    }                                                                         \
} while (0)

// Flush ring chunk [T0, T0+9] -> out.  480 float4 / 256 thr.
#define FLUSH(T0) do {                                                        \
    float4* po4_ = (float4*)(out + (size_t)base * 360);                       \
    _Pragma("unroll")                                                         \
    for (int q2 = 0; q2 < 2; ++q2) {                                          \
        int idx4 = q2 * 256 + tid;                                            \
        if (idx4 < 480) {                                                     \
            int a = idx4 / 30, rem = idx4 % 30;                               \
            int m = rem / 5, tq = rem % 5;                                    \
            int t0 = (T0) + tq * 2;                                           \
            int s0 = SLOT(t0), s1 = SLOT(t0 + 1);                             \
            half2v p0 = *(const half2v*)&predh[(a * 11 + s0) * 12 + 2 * m];   \
            half2v p1 = *(const half2v*)&predh[(a * 11 + s1) * 12 + 2 * m];   \
            float4 o;                                                         \
            o.x = (float)p0[0]; o.y = (float)p0[1];                           \
            o.z = (float)p1[0]; o.w = (float)p1[1];                           \
            po4_[a * 90 + m * 15 + ((T0) >> 1) + tq] = o;                     \
        }                                                                     \
    }                                                                         \
} while (0)

    for (int t = 0; t < TT; t += 2) {
        // even step t: pc=0, pn=1
        if (t == 10) FLUSH(0);
        else if (t == 20) FLUSH(10);
        PHASE_AB(0, 1);                       // S1
        __syncthreads();
        PHASE_C(1, t, 0);                     // S2
        __syncthreads();
        // odd step t+1: pc=1, pn=0
        PHASE_AB(1, 0);                       // S1
        __syncthreads();
        PHASE_C(0, t + 1, (t + 1) == TT - 1); // S2
        __syncthreads();
    }
    FLUSH(20);   // final chunk [20..29]; predh complete per last barrier

    // ---- conf = softmax(h_30 @ Wconf^T + bconf): wave 0 ----
    // h_30 lives in parity 0 (t=29 wrote PN=0), offset 32.
    if (wid == 0) {
        int r = lane >> 2, qq = lane & 3;   // agent, k-quarter
        float l[6];
#pragma unroll
        for (int md = 0; md < 6; ++md)
            l[md] = (qq == 0) ? ws[BCONF_OFF + md] : 0.f;
#pragma unroll
        for (int jj = 0; jj < 16; ++jj) {
            float hv = (float)zsh[r * 168 + 32 + qq * 16 + jj];
#pragma unroll
            for (int md = 0; md < 6; ++md)
                l[md] = fmaf(hv, ws[WCONF_OFF + md * 64 + qq * 16 + jj], l[md]);
        }
#pragma unroll
        for (int md = 0; md < 6; ++md) {
            l[md] += __shfl_xor(l[md], 1);
            l[md] += __shfl_xor(l[md], 2);
        }
        if (qq == 0) {
            float mx = l[0];
#pragma unroll
            for (int md = 1; md < 6; ++md) mx = fmaxf(mx, l[md]);
            float ex[6], s = 0.f;
#pragma unroll
            for (int md = 0; md < 6; ++md) { ex[md] = __expf(l[md] - mx); s += ex[md]; }
            float inv = FRCP(s);
#pragma unroll
            for (int md = 0; md < 6; ++md)
                out[CONF_BASE + (size_t)(base + r) * 6 + md] = ex[md] * inv;
        }
    }
}

extern "C" void kernel_launch(void* const* d_in, const int* in_sizes, int n_in,
                              void* d_out, int out_size, void* d_ws, size_t ws_size,
                              hipStream_t stream) {
    const void* traj_rel = d_in[1];
    const void* h0   = d_in[2];
    const void* c0   = d_in[3];
    const void* W_ih = d_in[4];
    const void* W_hh = d_in[5];
    const void* b_ih = d_in[6];
    const void* b_hh = d_in[7];
    const void* W_se = d_in[8];
    const void* b_se = d_in[9];
    const void* W_pos  = d_in[10];
    const void* b_pos  = d_in[11];
    const void* W_conf = d_in[12];
    const void* b_conf = d_in[13];
    float* ws = (float*)d_ws;
    float* out = (float*)d_out;

    detect_kernel<<<1, 256, 0, stream>>>((const unsigned short*)W_hh,
                                         (int*)(ws + FLAG_IDX));
    prep_kernel<<<40, 256, 0, stream>>>(W_ih, W_hh, b_ih, b_hh, W_se, b_se,
                                        W_pos, b_pos, W_conf, b_conf, ws);
    lstm_kernel<<<BATCH / 16, 256, 0, stream>>>(traj_rel, h0, c0, ws, out);
}

// Round 9
// 224.513 us; speedup vs baseline: 1.9981x; 1.9981x over previous
//
#include <hip/hip_runtime.h>
#include <hip/hip_bf16.h>

typedef _Float16 half8 __attribute__((ext_vector_type(8)));
typedef _Float16 half4 __attribute__((ext_vector_type(4)));
typedef _Float16 half2v __attribute__((ext_vector_type(2)));
typedef float float4v __attribute__((ext_vector_type(4)));

#define BATCH 32768
#define TT 30

#if __has_builtin(__builtin_amdgcn_exp2f)
#define FEXP2(x) __builtin_amdgcn_exp2f(x)
#else
#define FEXP2(x) __expf((x) * 0.6931471805599453f)
#endif
#if __has_builtin(__builtin_amdgcn_rcpf)
#define FRCP(x) __builtin_amdgcn_rcpf(x)
#else
#define FRCP(x) (1.0f / (x))
#endif

#define NLOG2E  -1.4426950408889634f
#define N2LOG2E -2.8853900817779268f

// ws offsets (floats). Gate weights PRESCALED (-log2e; gate g -2log2e).
// SWAPPED-OPERAND GEMMs: W frags = A operand (row=lane&15=unit),
// z frags = B operand (col=lane&15=agent).  D: lane holds 4 UNITS x 1 AGENT.
// Gate bias folded into the K-pad column: z[k=80]=1.0, W[k=80]=bias.
#define WFRAG_OFF 0        // f16[4 u][4 gate][3 ks][64 lane][8] = 24576 halves
#define WCF_OFF   12288    // f16[2 role][2 ks][64 lane][8] = 2048 halves
#define BIASB_OFF 13312    // f32[256]  (unused by lstm; kept)
#define SXY_OFF   13568    // f32[16][3]   (Sx, Sy, bse)
#define CBIAS_OFF 13616    // f32[2][16]   (role0: bpos|0, role1: bx)
#define WCONF_OFF 13648    // f32[384]
#define BCONF_OFF 14032    // f32[6]
#define FLAG_IDX  14038    // int: 1 => inputs fp32, 0 => bf16
#define CONF_BASE (BATCH * 360)

__global__ void detect_kernel(const unsigned short* __restrict__ raw,
                              int* __restrict__ flag_out) {
    __shared__ int sflag[256];
    int local = 0;
    for (int i = threadIdx.x; i < 16384; i += 256) {
        unsigned short u = raw[i];
        if ((u & 0x7F80u) == 0x7F80u) local = 1;
    }
    sflag[threadIdx.x] = local;
    __syncthreads();
    if (threadIdx.x == 0) {
        int f = 0;
        for (int i = 0; i < 256; ++i) f |= sflag[i];
        flag_out[0] = f;
    }
}

__device__ __forceinline__ float ldin(const void* p, int i, int isf32) {
    return isf32 ? ((const float*)p)[i]
                 : (float)((const __hip_bfloat16*)p)[i];
}

__global__ void prep_kernel(const void* __restrict__ W_ih,
                            const void* __restrict__ W_hh,
                            const void* __restrict__ b_ih,
                            const void* __restrict__ b_hh,
                            const void* __restrict__ W_se,
                            const void* __restrict__ b_se,
                            const void* __restrict__ W_pos,
                            const void* __restrict__ b_pos,
                            const void* __restrict__ W_conf,
                            const void* __restrict__ b_conf,
                            float* __restrict__ ws)
{
    const int isf32 = ((const int*)(ws + FLAG_IDX))[0];
    int tid = blockIdx.x * blockDim.x + threadIdx.x;
    int stride = gridDim.x * blockDim.x;
    _Float16* wfh = (_Float16*)ws;

    // Gate-GEMM W fragments, 16x16x32 tiles, K padded to 96.
    // k==80 carries the (prescaled) gate bias; z[k=80]=1 in the kernel.
    for (int idx = tid; idx < 24576; idx += stride) {
        int jj = idx & 7, r = idx >> 3;
        int lane = r & 63; r >>= 6;
        int ks = r % 3; r /= 3;
        int gate = r & 3; int uv = r >> 2;
        int col = lane & 15, akq = lane >> 4;
        int k = ks * 32 + akq * 8 + jj;
        int row = gate * 64 + uv * 16 + col;
        float v = 0.f;
        if (k < 16) v = ldin(W_ih, row * 16 + k, isf32);
        else if (k < 80) v = ldin(W_hh, row * 64 + (k - 16), isf32);
        else if (k == 80) v = ldin(b_ih, row, isf32) + ldin(b_hh, row, isf32);
        v *= (gate == 2) ? N2LOG2E : NLOG2E;
        wfh[idx] = (_Float16)v;
    }
    // Fused C-GEMM fragments: role0 = Wpos (rel), role1 = M=Wse*Wpos (x).
    _Float16* wch = (_Float16*)(ws + WCF_OFF);
    for (int idx = tid; idx < 2048; idx += stride) {
        int jj = idx & 7, r = idx >> 3;
        int lane = r & 63; r >>= 6;
        int ks = r & 1, role = r >> 1;
        int col = lane & 15, akq = lane >> 4;
        int k = ks * 32 + akq * 8 + jj;   // 0..63 over h
        float v = 0.f;
        if (role == 0) {
            if (col < 12) v = ldin(W_pos, col * 64 + k, isf32);
        } else {
            float s = 0.f;
            for (int p = 0; p < 12; ++p)
                s += ldin(W_se, col * 12 + p, isf32) * ldin(W_pos, p * 64 + k, isf32);
            v = s;
        }
        wch[idx] = (_Float16)v;
    }
    for (int idx = tid; idx < 256; idx += stride) {
        int gate = idx >> 6;
        float scale = (gate == 2) ? N2LOG2E : NLOG2E;
        ws[BIASB_OFF + idx] = (ldin(b_ih, idx, isf32) + ldin(b_hh, idx, isf32)) * scale;
    }
    for (int idx = tid; idx < 16; idx += stride) {
        float sx = 0.f, sy = 0.f;
        for (int m = 0; m < 6; ++m) {
            sx += ldin(W_se, idx * 12 + 2 * m, isf32);
            sy += ldin(W_se, idx * 12 + 2 * m + 1, isf32);
        }
        ws[SXY_OFF + idx * 3 + 0] = sx;
        ws[SXY_OFF + idx * 3 + 1] = sy;
        ws[SXY_OFF + idx * 3 + 2] = ldin(b_se, idx, isf32);
    }
    for (int idx = tid; idx < 32; idx += stride) {
        int w = idx >> 4, cc = idx & 15;
        float v = 0.f;
        if (w == 0) {
            if (cc < 12) v = ldin(b_pos, cc, isf32);
        } else {
            float s = ldin(b_se, cc, isf32);
            for (int p = 0; p < 12; ++p)
                s += ldin(W_se, cc * 12 + p, isf32) * ldin(b_pos, p, isf32);
            v = s;
        }
        ws[CBIAS_OFF + idx] = v;
    }
    for (int idx = tid; idx < 384; idx += stride)
        ws[WCONF_OFF + idx] = ldin(W_conf, idx, isf32);
    for (int idx = tid; idx < 6; idx += stride)
        ws[BCONF_OFF + idx] = ldin(b_conf, idx, isf32);
}

// WAVE-AUTONOMOUS, ZERO LOOP BARRIERS: block = 256 thr (4 waves), each wave
// owns 16 agents for the entire recurrence.  All hazards are same-wave
// program-order DS dependencies (h-write -> read, x-write -> read, ring
// write -> flush read), so waves slip freely; the 8 waves/CU (2 blocks) are
// mutually unsynchronized.  Gate W (48 KB) staged once into block-shared
// LDS, read per-MFMA via compile-time offsets (lane-linear, conflict-free).
// Per-wave z strip [16 agents][104 halves]: [x 0..15 | pad 16..31 (16->1.0
// bias) | h 32..95] -- single-buffered (in-wave order, no WAR).  pred goes
// to a per-wave 10-slot LDS ring, flushed as coalesced float4 at t=10/20/
// end (flush reads precede slot reuse in program order -> 10 slots suffice).
__global__ __launch_bounds__(256, 2) void lstm_kernel(
    const void* __restrict__ traj_rel,
    const void* __restrict__ h0,
    const void* __restrict__ c0,
    const float* __restrict__ ws,
    float* __restrict__ out)
{
    __shared__ __align__(16) _Float16 wlds[24576];    // 48 KB gate W frags
    __shared__ __align__(16) _Float16 zsh[4 * 1664];  // 4 waves x [16][104]
    __shared__ __align__(16) _Float16 ring[4 * 1920]; // 4 x [16 ag][10][12]

    const int tid = threadIdx.x;
    const int lane = tid & 63;
    const int wid = __builtin_amdgcn_readfirstlane(tid >> 6);  // wave 0..3
    const int col16 = lane & 15;        // agent (D col)
    const int akq = lane >> 4;          // 0..3 (D row quarter / k chunk)
    const int wbase = blockIdx.x * 64 + wid * 16;   // wave's first agent
    const int isf32 = ((const int*)(ws + FLAG_IDX))[0];

    // ---- stage gate W fragments into LDS (3072 float4 / 256 thr) ----
    {
        const float4* src = (const float4*)ws;
        float4* dst = (float4*)wlds;
#pragma unroll
        for (int k = 0; k < 12; ++k)
            dst[k * 256 + tid] = src[k * 256 + tid];
    }

    _Float16* const zw = &zsh[wid * 1664];
    _Float16* const ringw = &ring[wid * 1920];

    // ---- per-lane constants ----
    half8 wfcR[2], wfcX[2];
    {
        const float4v* wcg = (const float4v*)(ws + WCF_OFF);
#pragma unroll
        for (int ks = 0; ks < 2; ++ks) {
            wfcR[ks] = __builtin_bit_cast(half8, wcg[ks * 64 + lane]);
            wfcX[ks] = __builtin_bit_cast(half8, wcg[(2 + ks) * 64 + lane]);
        }
    }
    const float4v cbR4 = *(const float4v*)&ws[CBIAS_OFF + akq * 4];
    const float4v cbX4 = *(const float4v*)&ws[CBIAS_OFF + 16 + akq * 4];

    // ---- c state: 16 cells/lane (agent col16, unit u*16 + akq*4 + i) ----
    float c[16];
#pragma unroll
    for (int u = 0; u < 4; ++u)
#pragma unroll
        for (int i = 0; i < 4; ++i)
            c[u * 4 + i] = ldin(c0, (wbase + col16) * 64 + u * 16 + akq * 4 + i, isf32);

    // ---- init own z strip: h0, x0, bias pad (k80 = 1.0) ----
    {
        int row = lane & 15, part = lane >> 4;   // agent row, quarter
        _Float16* zr = zw + row * 104;
        int ag = wbase + row;
        half8 ha, hb;
#pragma unroll
        for (int i = 0; i < 8; ++i) {
            ha[i] = (_Float16)ldin(h0, ag * 64 + part * 16 + i, isf32);
            hb[i] = (_Float16)ldin(h0, ag * 64 + part * 16 + 8 + i, isf32);
        }
        *(half8*)&zr[32 + part * 16] = ha;
        *(half8*)&zr[32 + part * 16 + 8] = hb;
        if (part < 2) {
            float rx = ldin(traj_rel, 2 * ag, isf32);
            float ry = ldin(traj_rel, 2 * ag + 1, isf32);
            half8 xs;
#pragma unroll
            for (int i = 0; i < 8; ++i) {
                int e = part * 8 + i;
                float x = fmaf(rx, ws[SXY_OFF + e * 3],
                          fmaf(ry, ws[SXY_OFF + e * 3 + 1], ws[SXY_OFF + e * 3 + 2]));
                xs[i] = (_Float16)(x > 0.f ? x : 0.01f * x);
            }
            *(half8*)&zr[part * 8] = xs;
        } else if (part == 2) {     // k = 80..87: bias column (k80 = 1.0)
            half8 zz = {};
            zz[0] = (_Float16)1.0f;
            *(half8*)&zr[16] = zz;
        } else {                    // k = 88..95: zeros
            half8 zz = {};
            *(half8*)&zr[24] = zz;
        }
    }
    __syncthreads();   // W + strips staged; the ONLY barrier in the kernel

    // ---- precomputed addresses (halves) ----
    int aoffv[3];   // z B-frag base per ks (k-chunk map)
#pragma unroll
    for (int ks = 0; ks < 3; ++ks) {
        int q = ks * 4 + akq;          // global k-chunk 0..11
        int off = (q < 2) ? q * 8
                : (q < 10) ? 32 + (q - 2) * 8
                           : 16 + (q - 10) * 8;
        aoffv[ks] = col16 * 104 + off;
    }
    const int ahb = col16 * 104 + 32 + akq * 8;   // C h-read (+ks*32)
    const int hwb = col16 * 104 + 32 + akq * 4;   // h-write (+u*16)
    const int xwb = col16 * 104 + akq * 4;        // x-write

// Flush ring chunk [T0, T0+9] -> out.  Per wave: 480 float4, slots are
// relative (t - T0 = tq*2).  Runs of 5 consecutive float4 per (a,m).
#define FLUSH(T0) do {                                                        \
    float4* po4_ = (float4*)(out + (size_t)wbase * 360);                      \
    _Pragma("unroll")                                                         \
    for (int it = 0; it < 8; ++it) {                                          \
        int idx4 = it * 64 + lane;                                            \
        if (idx4 < 480) {                                                     \
            int a = idx4 / 30, rem = idx4 % 30;                               \
            int m = rem / 5, tq = rem % 5;                                    \
            half2v p0 = *(const half2v*)&ringw[(a * 10 + tq * 2) * 12 + 2 * m];\
            half2v p1 = *(const half2v*)&ringw[(a * 10 + tq * 2 + 1) * 12 + 2 * m];\
            float4 o;                                                         \
            o.x = (float)p0[0]; o.y = (float)p0[1];                           \
            o.z = (float)p1[0]; o.w = (float)p1[1];                           \
            po4_[a * 90 + m * 15 + ((T0) >> 1) + tq] = o;                     \
        }                                                                     \
    }                                                                         \
} while (0)

#pragma unroll 1
    for (int t = 0; t < TT; ++t) {
        if (t == 10) FLUSH(0);
        else if (t == 20) FLUSH(10);

        // ---- z B-frags (k = 0..95, reads precede h overwrite in order) ----
        half8 az0 = *(const half8*)&zw[aoffv[0]];
        half8 az1 = *(const half8*)&zw[aoffv[1]];
        half8 az2 = *(const half8*)&zw[aoffv[2]];

        // ---- gates + activations per unit-tile u (units u*16..u*16+16) ----
#pragma unroll
        for (int u = 0; u < 4; ++u) {
            float4v acc[4];
#pragma unroll
            for (int g = 0; g < 4; ++g) {
                acc[g][0] = 0.f; acc[g][1] = 0.f;
                acc[g][2] = 0.f; acc[g][3] = 0.f;
            }
#pragma unroll
            for (int g = 0; g < 4; ++g) {
                const int fb = ((u * 4 + g) * 3) * 512 + lane * 8;
                acc[g] = __builtin_amdgcn_mfma_f32_16x16x32_f16(
                    *(const half8*)&wlds[fb], az0, acc[g], 0, 0, 0);
                acc[g] = __builtin_amdgcn_mfma_f32_16x16x32_f16(
                    *(const half8*)&wlds[fb + 512], az1, acc[g], 0, 0, 0);
                acc[g] = __builtin_amdgcn_mfma_f32_16x16x32_f16(
                    *(const half8*)&wlds[fb + 1024], az2, acc[g], 0, 0, 0);
            }
            half4 hv;
#pragma unroll
            for (int i = 0; i < 4; ++i) {
                float ei = FEXP2(acc[0][i]);
                float ef = FEXP2(acc[1][i]);
                float eg = FEXP2(acc[2][i]);
                float eo = FEXP2(acc[3][i]);
                float pp = (1.f + ei) * (1.f + eg);
                float qq = 1.f + ef;
                float cn = fmaf(c[u * 4 + i], pp, (1.f - eg) * qq) * FRCP(pp * qq);
                c[u * 4 + i] = cn;
                float ec = FEXP2(cn * N2LOG2E);
                float hn = (1.f - ec) * FRCP((1.f + eo) * (1.f + ec));
                hv[i] = (_Float16)hn;
            }
            *(half4*)&zw[hwb + u * 16] = hv;
        }

        // ---- C-GEMM on h(t+1) (same-wave in-order LDS) ----
        half8 ah0 = *(const half8*)&zw[ahb];
        half8 ah1 = *(const half8*)&zw[ahb + 32];
        {   // rel -> ring
            float4v rr;
            rr[0] = cbR4[0]; rr[1] = cbR4[1]; rr[2] = cbR4[2]; rr[3] = cbR4[3];
            rr = __builtin_amdgcn_mfma_f32_16x16x32_f16(wfcR[0], ah0, rr, 0, 0, 0);
            rr = __builtin_amdgcn_mfma_f32_16x16x32_f16(wfcR[1], ah1, rr, 0, 0, 0);
            if (akq < 3) {
                int st = t - (t >= 20 ? 20 : t >= 10 ? 10 : 0);
                half4 pv;
#pragma unroll
                for (int i = 0; i < 4; ++i) pv[i] = (_Float16)rr[i];
                *(half4*)&ringw[(col16 * 10 + st) * 12 + akq * 4] = pv;
            }
        }
        if (t != TT - 1) {   // x feedback -> z cols 0..15
            float4v rx;
            rx[0] = cbX4[0]; rx[1] = cbX4[1]; rx[2] = cbX4[2]; rx[3] = cbX4[3];
            rx = __builtin_amdgcn_mfma_f32_16x16x32_f16(wfcX[0], ah0, rx, 0, 0, 0);
            rx = __builtin_amdgcn_mfma_f32_16x16x32_f16(wfcX[1], ah1, rx, 0, 0, 0);
            half4 xv4;
#pragma unroll
            for (int i = 0; i < 4; ++i) {
                float xv = rx[i];
                xv4[i] = (_Float16)(xv > 0.f ? xv : 0.01f * xv);
            }
            *(half4*)&zw[xwb] = xv4;
        }
    }
    FLUSH(20);   // final chunk [20..29]

    // ---- conf = softmax(h_30 @ Wconf^T + bconf), per wave, no barrier ----
    {
        int r = lane >> 2, qq = lane & 3;   // agent r, k-quarter qq
        float l[6];
#pragma unroll
        for (int md = 0; md < 6; ++md)
            l[md] = (qq == 0) ? ws[BCONF_OFF + md] : 0.f;
#pragma unroll
        for (int jj = 0; jj < 16; ++jj) {
            float hv = (float)zw[r * 104 + 32 + qq * 16 + jj];
#pragma unroll
            for (int md = 0; md < 6; ++md)
                l[md] = fmaf(hv, ws[WCONF_OFF + md * 64 + qq * 16 + jj], l[md]);
        }
#pragma unroll
        for (int md = 0; md < 6; ++md) {
            l[md] += __shfl_xor(l[md], 1);
            l[md] += __shfl_xor(l[md], 2);
        }
        if (qq == 0) {
            float mx = l[0];
#pragma unroll
            for (int md = 1; md < 6; ++md) mx = fmaxf(mx, l[md]);
            float ex[6], s = 0.f;
#pragma unroll
            for (int md = 0; md < 6; ++md) { ex[md] = __expf(l[md] - mx); s += ex[md]; }
            float inv = FRCP(s);
#pragma unroll
            for (int md = 0; md < 6; ++md)
                out[CONF_BASE + (size_t)(wbase + r) * 6 + md] = ex[md] * inv;
        }
    }
}

extern "C" void kernel_launch(void* const* d_in, const int* in_sizes, int n_in,
                              void* d_out, int out_size, void* d_ws, size_t ws_size,
                              hipStream_t stream) {
    const void* traj_rel = d_in[1];
    const void* h0   = d_in[2];
    const void* c0   = d_in[3];
    const void* W_ih = d_in[4];
    const void* W_hh = d_in[5];
    const void* b_ih = d_in[6];
    const void* b_hh = d_in[7];
    const void* W_se = d_in[8];
    const void* b_se = d_in[9];
    const void* W_pos  = d_in[10];
    const void* b_pos  = d_in[11];
    const void* W_conf = d_in[12];
    const void* b_conf = d_in[13];
    float* ws = (float*)d_ws;
    float* out = (float*)d_out;

    detect_kernel<<<1, 256, 0, stream>>>((const unsigned short*)W_hh,
                                         (int*)(ws + FLAG_IDX));
    prep_kernel<<<40, 256, 0, stream>>>(W_ih, W_hh, b_ih, b_hh, W_se, b_se,
                                        W_pos, b_pos, W_conf, b_conf, ws);
    lstm_kernel<<<BATCH / 64, 256, 0, stream>>>(traj_rel, h0, c0, ws, out);
}